// Round 10
// baseline (62834.625 us; speedup 1.0000x reference)
//
#include <hip/hip_runtime.h>

#define L 64
#define TLEN 200000
#define CH 528                        // divisible by 8; checkpoint cadence
#define NCH 379                       // ceil(200000/528); 378*528 = 199584
#define LASTLEN (TLEN - (NCH - 1) * CH)   // 416 (divisible by 8)
#define NEGV -10000.0f
#define STARTT 62
#define STOPT 63

// workspace layout (bytes) — total 123052 < 126940 proven available
#define CKPT_OFF 0                          // float[(NCH+1)*L]  = 97280 B
#define M_OFF ((NCH + 1) * L * 4)           // uchar[NCH*L]      = 24256 B
#define ETAG_OFF (M_OFF + NCH * L)          // int[NCH]          = 1516 B

typedef float f32x4 __attribute__((ext_vector_type(4)));

// Drained barrier: init only (plain ds_writes must be globally visible).
#define WAVE_BARRIER() __asm__ volatile("s_waitcnt lgkmcnt(0)\ns_barrier" ::: "memory")
// Per-step barrier WITHOUT lgkmcnt drain — validated rounds 3-9 (absmax 0,
// atomic and plain-write variants): pre-barrier LDS ops are serviced before
// post-barrier LDS ops reach the pipe.
#define FAST_BARRIER() __asm__ volatile("s_barrier" ::: "memory")
#define STEP_BARRIER() __asm__ volatile("" ::: "memory")

// force v_max3_f32 (3-input max, 1 instruction); max is order-invariant over
// finite floats so every tree below is bit-identical to pairwise fmax.
__device__ __forceinline__ float max3f(float a, float b, float c) {
    float r;
    __asm__("v_max3_f32 %0, %1, %2, %3" : "=v"(r) : "v"(a), "v"(b), "v"(c));
    return r;
}

// componentwise max3 / fmax on f32x4 (expands to 4 scalar instrs each)
__device__ __forceinline__ f32x4 vmax3q(f32x4 a, f32x4 b, f32x4 c) {
    f32x4 r;
    r.x = max3f(a.x, b.x, c.x);
    r.y = max3f(a.y, b.y, c.y);
    r.z = max3f(a.z, b.z, c.z);
    r.w = max3f(a.w, b.w, c.w);
    return r;
}
__device__ __forceinline__ f32x4 vmaxq(f32x4 a, f32x4 b) {
    f32x4 r;
    r.x = fmaxf(a.x, b.x);
    r.y = fmaxf(a.y, b.y);
    r.z = fmaxf(a.z, b.z);
    r.w = fmaxf(a.w, b.w);
    return r;
}

// ---------------------------------------------------------------------------
// Pass 1: exact sequential forward recurrence (the critical path).
// 4 waves (256 threads), p-split, ONE LDS TRIP PER STEP:
// R3/R9 both measure exactly 352 cy/step with a read + ds_max-RMW trip pair;
// VALU deltas (92 vs 35 cy) don't move the period (R9 null) => the period is
// {barrier + read latency + RMW service}. This variant deletes the RMW:
//   write side: wave w plain-writes its feat-included partial row
//     pm[WR][w][n] = RN(max_{p in slice_w}(RN(v_{t-1}[p]+T[n][p])) + f_t[n])
//     (stride-1, 2-way banks = free; no atomic, no reset, full overwrite)
//   read side: lane fuses the 4-row combine into its slice load: 16 broadcast
//     ds_read_b128 (4 rows x 4 quads of slice [16w,16w+16), uniform address
//     per wave = conflict-free, latencies overlapped) -> row-max -> +T ->
//     tree -> next partial.
// v_t[p] = max_r pm[r][p] is exact by the monotone-RN identity (validated
// R3-R9): max_w RN(part_w + f) == RN(max_w part_w + f). Every score is one
// RN(v+T); maxes are order-invariant => checkpoints match the reference
// bit-for-bit; replay kernels unchanged. 200000 % 8 == 0 -> no tail; step t
// reads buf t%2, writes (t+1)%2; checkpoints (CH%8==0) always read buf 0.
// ---------------------------------------------------------------------------
__global__ __launch_bounds__(256, 1) void k_forward(const float* __restrict__ feats,
                                                    const float* __restrict__ trans,
                                                    float* __restrict__ ckpt) {
    const int tid = threadIdx.x;
    const int n = tid & 63;   // next-tag owned by this lane
    const int w = tid >> 6;   // wave id = prev-slice
    const int sb = 16 * w;    // first prev-tag of this wave's slice

    // T[n][16w .. 16w+16) — 4 quads; pin keeps them VGPR-resident (proven).
    const f32x4* t4 = reinterpret_cast<const f32x4*>(trans) + n * 16 + w * 4;
    f32x4 q0 = t4[0], q1 = t4[1], q2 = t4[2], q3 = t4[3];
    __asm__ volatile("" : "+v"(q0), "+v"(q1), "+v"(q2), "+v"(q3));

    // pm[buf][row=wave][n]; writes stride-1 (2-way free); reads broadcast
    __shared__ __align__(16) float pm[2][4][L];

    // init: every row of buf 0 holds v_{-1} (so max_r == v_{-1})
    pm[0][w][n] = (n == STARTT) ? 0.0f : NEGV;
    WAVE_BARRIER();

    float fc[8];
#pragma unroll
    for (int j = 0; j < 8; ++j) fc[j] = feats[j * L + n];

    int nextck = 0, cidx = 0;

#define FWD_STEP(RD, WR, FEAT)                                                 \
    do {                                                                       \
        const f32x4 r0a = *reinterpret_cast<const f32x4*>(&pm[RD][0][sb + 0]); \
        const f32x4 r1a = *reinterpret_cast<const f32x4*>(&pm[RD][1][sb + 0]); \
        const f32x4 r2a = *reinterpret_cast<const f32x4*>(&pm[RD][2][sb + 0]); \
        const f32x4 r3a = *reinterpret_cast<const f32x4*>(&pm[RD][3][sb + 0]); \
        const f32x4 r0b = *reinterpret_cast<const f32x4*>(&pm[RD][0][sb + 4]); \
        const f32x4 r1b = *reinterpret_cast<const f32x4*>(&pm[RD][1][sb + 4]); \
        const f32x4 r2b = *reinterpret_cast<const f32x4*>(&pm[RD][2][sb + 4]); \
        const f32x4 r3b = *reinterpret_cast<const f32x4*>(&pm[RD][3][sb + 4]); \
        const f32x4 r0c = *reinterpret_cast<const f32x4*>(&pm[RD][0][sb + 8]); \
        const f32x4 r1c = *reinterpret_cast<const f32x4*>(&pm[RD][1][sb + 8]); \
        const f32x4 r2c = *reinterpret_cast<const f32x4*>(&pm[RD][2][sb + 8]); \
        const f32x4 r3c = *reinterpret_cast<const f32x4*>(&pm[RD][3][sb + 8]); \
        const f32x4 r0d = *reinterpret_cast<const f32x4*>(&pm[RD][0][sb + 12]);\
        const f32x4 r1d = *reinterpret_cast<const f32x4*>(&pm[RD][1][sb + 12]);\
        const f32x4 r2d = *reinterpret_cast<const f32x4*>(&pm[RD][2][sb + 12]);\
        const f32x4 r3d = *reinterpret_cast<const f32x4*>(&pm[RD][3][sb + 12]);\
        const f32x4 sa = vmaxq(vmax3q(r0a, r1a, r2a), r3a) + q0;               \
        const f32x4 sbq = vmaxq(vmax3q(r0b, r1b, r2b), r3b) + q1;              \
        const f32x4 sc = vmaxq(vmax3q(r0c, r1c, r2c), r3c) + q2;               \
        const f32x4 sd = vmaxq(vmax3q(r0d, r1d, r2d), r3d) + q3;               \
        const float m0 = max3f(fmaxf(sa.x, sa.y), sa.z, sa.w);                 \
        const float m1 = max3f(fmaxf(sbq.x, sbq.y), sbq.z, sbq.w);             \
        const float m2 = max3f(fmaxf(sc.x, sc.y), sc.z, sc.w);                 \
        const float m3 = max3f(fmaxf(sd.x, sd.y), sd.z, sd.w);                 \
        const float pmv = fmaxf(max3f(m0, m1, m2), m3) + (FEAT);               \
        pm[WR][w][n] = pmv;                                                    \
        FAST_BARRIER();                                                        \
    } while (0)

    for (int tb = 0; tb < TLEN; tb += 8) {
        if (tb == nextck) {
            // v_{tb-1}[n] = max over rows of pm[0] (tb even -> read-buf 0)
            const float c0 = pm[0][0][n];
            const float c1 = pm[0][1][n];
            const float c2 = pm[0][2][n];
            const float c3 = pm[0][3][n];
            if (w == 0) ckpt[cidx * L + n] = fmaxf(max3f(c0, c1, c2), c3);
            nextck += CH;
            ++cidx;
        }
        float fn_[8];
        const bool more = (tb + 8) < TLEN;
        if (more) {
#pragma unroll
            for (int j = 0; j < 8; ++j) fn_[j] = feats[(tb + 8 + j) * L + n];
        }
        FWD_STEP(0, 1, fc[0]);
        FWD_STEP(1, 0, fc[1]);
        FWD_STEP(0, 1, fc[2]);
        FWD_STEP(1, 0, fc[3]);
        FWD_STEP(0, 1, fc[4]);
        FWD_STEP(1, 0, fc[5]);
        FWD_STEP(0, 1, fc[6]);
        FWD_STEP(1, 0, fc[7]);
        if (more) {
#pragma unroll
            for (int j = 0; j < 8; ++j) fc[j] = fn_[j];
        }
    }
    // v_{199999}[n] = max over rows of pm[0] (step 199999 wrote buf 0)
    {
        const float c0 = pm[0][0][n];
        const float c1 = pm[0][1][n];
        const float c2 = pm[0][2][n];
        const float c3 = pm[0][3][n];
        if (w == 0) ckpt[NCH * L + n] = fmaxf(max3f(c0, c1, c2), c3);
    }
#undef FWD_STEP
}

// ---------------------------------------------------------------------------
// helpers for the replay kernels (off the critical path, ~0.8 ms total)
// ---------------------------------------------------------------------------
__device__ __forceinline__ void load_trow(const float* __restrict__ trans, int n, float* trow) {
#pragma unroll
    for (int i = 0; i < 16; ++i) {
        const f32x4 q = reinterpret_cast<const f32x4*>(trans)[n * 16 + i];
        trow[4 * i + 0] = q.x;
        trow[4 * i + 1] = q.y;
        trow[4 * i + 2] = q.z;
        trow[4 * i + 3] = q.w;
    }
}

// Bit-exact chunk replay from checkpoint; records backpointers into LDS.
// Single wave per block; in-order DS pipe makes ds_write->ds_read safe with
// only a compiler barrier. Argmax is an in-order strictly-greater scan =>
// first-max, matching jnp.argmax; v matches k_forward bit-for-bit (max is
// order-invariant, +feat monotone-exact).
__device__ __forceinline__ void replay_chunk(const float* __restrict__ feats,
                                             const float* __restrict__ ckpt,
                                             const float* trow, float* vsh,
                                             unsigned char* bpl, int c, int len, int n) {
    float vreg = ckpt[c * L + n];
    vsh[n] = vreg;
    STEP_BARRIER();
    const int base = c * CH;

    float fc[8];
#pragma unroll
    for (int j = 0; j < 8; ++j) fc[j] = feats[(base + j) * L + n];

    for (int sb = 0; sb < len; sb += 8) {
        float fn_[8];
        const bool more = (sb + 8) < len;
        if (more) {
#pragma unroll
            for (int j = 0; j < 8; ++j) fn_[j] = feats[(base + sb + 8 + j) * L + n];
        }
#pragma unroll
        for (int j = 0; j < 8; ++j) {
            float mc[4];
            int ic[4];
#pragma unroll
            for (int g = 0; g < 4; ++g) {
                float m = -INFINITY;
                int idx = g * 16;
#pragma unroll
                for (int r = 0; r < 4; ++r) {
                    const int pb = g * 16 + r * 4;
                    const f32x4 vv = *reinterpret_cast<const f32x4*>(vsh + pb);
                    const float a = vv.x + trow[pb + 0];
                    const float b = vv.y + trow[pb + 1];
                    const float cc = vv.z + trow[pb + 2];
                    const float d = vv.w + trow[pb + 3];
                    if (a > m)  { m = a;  idx = pb + 0; }
                    if (b > m)  { m = b;  idx = pb + 1; }
                    if (cc > m) { m = cc; idx = pb + 2; }
                    if (d > m)  { m = d;  idx = pb + 3; }
                }
                mc[g] = m;
                ic[g] = idx;
            }
            float m = mc[0];
            int idx = ic[0];
            if (mc[1] > m) { m = mc[1]; idx = ic[1]; }
            if (mc[2] > m) { m = mc[2]; idx = ic[2]; }
            if (mc[3] > m) { m = mc[3]; idx = ic[3]; }

            vreg = m + fc[j];
            bpl[(sb + j) * L + n] = (unsigned char)idx;
            vsh[n] = vreg;
            STEP_BARRIER();
        }
        if (more) {
#pragma unroll
            for (int j = 0; j < 8; ++j) fc[j] = fn_[j];
        }
    }
}

// ---------------------------------------------------------------------------
// Pass 2: per-chunk bit-exact replay -> backpointers -> 64-entry chunk map.
// M[c*64+e] = tag at (c*CH - 1) given tag e at the last step of chunk c.
// ---------------------------------------------------------------------------
__global__ __launch_bounds__(64, 1) void k_maps(const float* __restrict__ feats,
                                                const float* __restrict__ trans,
                                                const float* __restrict__ ckpt,
                                                unsigned char* __restrict__ M) {
    const int c = blockIdx.x;
    const int n = threadIdx.x;
    const int len = (c == NCH - 1) ? LASTLEN : CH;

    __shared__ __align__(16) float vsh[L];
    __shared__ unsigned char bpl[CH * L];

    float trow[L];
    load_trow(trans, n, trow);
    replay_chunk(feats, ckpt, trow, vsh, bpl, c, len, n);
    __syncthreads();

    int tag = n;
    for (int s = len - 1; s >= 0; --s) tag = bpl[s * L + tag];
    M[c * L + n] = (unsigned char)tag;
}

// ---------------------------------------------------------------------------
// Pass 3: terminal argmax (bit-exact score) + back-to-front map composition.
// ---------------------------------------------------------------------------
__global__ __launch_bounds__(64, 1) void k_stitch(const float* __restrict__ trans,
                                                  const float* __restrict__ ckpt,
                                                  const unsigned char* __restrict__ M,
                                                  int* __restrict__ etag,
                                                  float* __restrict__ out) {
    const int n = threadIdx.x;
    __shared__ float tsh[L];
    __shared__ int bsh;
    __shared__ __align__(16) unsigned char msh[NCH * L];

    tsh[n] = ckpt[NCH * L + n] + trans[STOPT * L + n];  // terminal[n]
    __syncthreads();
    if (n == 0) {
        float m = tsh[0];
        int b = 0;
        for (int p = 1; p < L; ++p)
            if (tsh[p] > m) { m = tsh[p]; b = p; }  // first-max, like jnp.argmax
        out[0] = m;   // path_score, bit-exact
        bsh = b;
    }
    __syncthreads();

    for (int i = n; i < (NCH * L) / 4; i += L)
        reinterpret_cast<int*>(msh)[i] = reinterpret_cast<const int*>(M)[i];
    __syncthreads();

    if (n == 0) {
        int carry = bsh;  // tag at t = T-1 = end of chunk NCH-1
        for (int c = NCH - 1; c >= 1; --c) {
            etag[c] = carry;
            carry = msh[c * L + carry];
        }
        etag[0] = carry;
    }
}

// ---------------------------------------------------------------------------
// Pass 4: per-chunk replay again, walk backwards from etag[c], emit path.
// Path written as float32 (harness reads the concatenated output as float).
// ---------------------------------------------------------------------------
__global__ __launch_bounds__(64, 1) void k_emit(const float* __restrict__ feats,
                                                const float* __restrict__ trans,
                                                const float* __restrict__ ckpt,
                                                const int* __restrict__ etag,
                                                float* __restrict__ out) {
    const int c = blockIdx.x;
    const int n = threadIdx.x;
    const int len = (c == NCH - 1) ? LASTLEN : CH;

    __shared__ __align__(16) float vsh[L];
    __shared__ unsigned char bpl[CH * L];
    __shared__ unsigned char plc[CH];

    float trow[L];
    load_trow(trans, n, trow);
    replay_chunk(feats, ckpt, trow, vsh, bpl, c, len, n);
    __syncthreads();

    int tag = etag[c];  // uniform; bpl reads below broadcast (same address)
    for (int s = len - 1; s >= 0; --s) {
        if (n == 0) plc[s] = (unsigned char)tag;
        tag = bpl[s * L + tag];
    }
    __syncthreads();

    for (int i = n; i < len; i += L)
        out[1 + c * CH + i] = (float)plc[i];
}

// ---------------------------------------------------------------------------
extern "C" void kernel_launch(void* const* d_in, const int* in_sizes, int n_in,
                              void* d_out, int out_size, void* d_ws, size_t ws_size,
                              hipStream_t stream) {
    const float* feats = (const float*)d_in[0];   // (1, T, L) fp32
    const float* trans = (const float*)d_in[1];   // (L, L) fp32
    float* out = (float*)d_out;                   // [score, path(T) as float]
    char* ws = (char*)d_ws;
    float* ckpt = (float*)(ws + CKPT_OFF);
    unsigned char* M = (unsigned char*)(ws + M_OFF);
    int* etag = (int*)(ws + ETAG_OFF);

    hipLaunchKernelGGL(k_forward, dim3(1), dim3(256), 0, stream, feats, trans, ckpt);
    hipLaunchKernelGGL(k_maps, dim3(NCH), dim3(64), 0, stream, feats, trans, ckpt, M);
    hipLaunchKernelGGL(k_stitch, dim3(1), dim3(64), 0, stream, trans, ckpt, M, etag, out);
    hipLaunchKernelGGL(k_emit, dim3(NCH), dim3(64), 0, stream, feats, trans, ckpt, etag, out);
}

// Round 11
// 30184.741 us; speedup vs baseline: 2.0817x; 2.0817x over previous
//
#include <hip/hip_runtime.h>

#define L 64
#define TLEN 200000
#define CH 528                        // divisible by 6 (fwd unroll) and 8 (replay unroll)
#define NCH 379                       // ceil(200000/528); 378*528 = 199584
#define LASTLEN (TLEN - (NCH - 1) * CH)   // 416 (divisible by 8)
#define MAINT 199992                  // 6*33332, main-loop trip; tail = 8 steps
#define NEGV -10000.0f
#define STARTT 62
#define STOPT 63

// workspace layout (bytes) — total 123052 < 126940 proven available
#define CKPT_OFF 0                          // float[(NCH+1)*L]  = 97280 B
#define M_OFF ((NCH + 1) * L * 4)           // uchar[NCH*L]      = 24256 B
#define ETAG_OFF (M_OFF + NCH * L)          // int[NCH]          = 1516 B

typedef float f32x4 __attribute__((ext_vector_type(4)));

// Drained barrier: init only (plain ds_writes must be globally visible).
#define WAVE_BARRIER() __asm__ volatile("s_waitcnt lgkmcnt(0)\ns_barrier" ::: "memory")
// Per-step barrier WITHOUT lgkmcnt drain — validated rounds 3-10 (absmax 0,
// atomic and plain-write variants): pre-barrier LDS ops are serviced before
// post-barrier LDS ops reach the pipe.
#define FAST_BARRIER() __asm__ volatile("s_barrier" ::: "memory")
#define STEP_BARRIER() __asm__ volatile("" ::: "memory")

// force v_max3_f32 (3-input max, 1 instruction); max is order-invariant over
// finite floats so every tree below is bit-identical to pairwise fmax.
__device__ __forceinline__ float max3f(float a, float b, float c) {
    float r;
    __asm__("v_max3_f32 %0, %1, %2, %3" : "=v"(r) : "v"(a), "v"(b), "v"(c));
    return r;
}

// ---------------------------------------------------------------------------
// Pass 1: exact sequential forward recurrence (the critical path).
// EIGHT waves (512 threads), p-split: wave w owns prev-tags [8w, 8w+8).
// BEST MEASURED STRUCTURE (R9: 352 cy/step, 29.3 ms). The structure space
// is mapped (R3-R10): the period is pure exchange machinery {barrier release
// + ds_read latency + ds_max RMW service}; VALU is fully hidden (R3 with 92
// VALU-cy == R9 with 35); every alternative (plain-write + DPP/RL/read-side
// combine) regressed. This is the structural floor at HIP source level.
// Step s reads buf s%3, atomics into (s+1)%3, wave0 resets (s+2)%3 (reset
// after the atomic: still pre-barrier, ordered before next step's atomics by
// the validated no-drain property; RS != RD so this step's reads unaffected).
// Bit-exactness: each score is one RN(v[p]+T[n][p]); max (incl. ds_max
// combine) is order-invariant over finite floats; +feat is applied to the
// per-wave partial max BEFORE the atomic — exact because RN is monotone:
// max_w RN(pm_w + f) == RN((max_w pm_w) + f). Checkpoints match the
// reference bit-for-bit; replay kernels unchanged.
// ---------------------------------------------------------------------------
__global__ __launch_bounds__(512, 1) void k_forward(const float* __restrict__ feats,
                                                    const float* __restrict__ trans,
                                                    float* __restrict__ ckpt) {
    const int tid = threadIdx.x;
    const int n = tid & 63;   // next-tag owned by this lane
    const int w = tid >> 6;   // wave id = prev-slice (0..7)

    // T[n][8w .. 8w+8) — 8 floats, 2 quads; pin keeps them VGPR-resident
    // (R0-proven pattern at 4 quads; 2 is comfortably within budget).
    const f32x4* t4 = reinterpret_cast<const f32x4*>(trans) + n * 16 + w * 2;
    f32x4 q0 = t4[0], q1 = t4[1];
    __asm__ volatile("" : "+v"(q0), "+v"(q1));

    __shared__ __align__(16) float vbuf[3][L];

    vbuf[0][n] = (n == STARTT) ? 0.0f : NEGV;  // v_{-1}; same value from all waves
    vbuf[1][n] = -INFINITY;                    // receives step-0 atomics
    vbuf[2][n] = -INFINITY;
    WAVE_BARRIER();

    float fc[6];
#pragma unroll
    for (int j = 0; j < 6; ++j) fc[j] = feats[j * L + n];

    int nextck = 0, cidx = 0;

#define FWD_STEP(RD, WR, RS, FEAT)                                            \
    do {                                                                      \
        const f32x4 va0 = *reinterpret_cast<const f32x4*>(&vbuf[RD][8 * w + 0]); \
        const f32x4 va1 = *reinterpret_cast<const f32x4*>(&vbuf[RD][8 * w + 4]); \
        const f32x4 s0 = va0 + q0, s1 = va1 + q1;                             \
        const float m0 = max3f(fmaxf(s0.x, s0.y), s0.z, s0.w);                \
        const float m1 = max3f(fmaxf(s1.x, s1.y), s1.z, s1.w);                \
        const float cand = fmaxf(m0, m1) + (FEAT);                            \
        __hip_atomic_fetch_max(&vbuf[WR][n], cand, __ATOMIC_RELAXED,          \
                               __HIP_MEMORY_SCOPE_WORKGROUP);                 \
        if (w == 0) vbuf[RS][n] = -INFINITY;                                  \
        FAST_BARRIER();                                                       \
    } while (0)

    for (int tb = 0; tb < MAINT; tb += 6) {
        if (tb == nextck) {
            // vbuf[0] holds v_{tb-1} (tb%3==0 always; 528%6==0 keeps hits aligned)
            if (w == 0) ckpt[cidx * L + n] = vbuf[0][n];
            nextck += CH;
            ++cidx;
        }
        float fn_[6];
        const bool more = (tb + 6) < MAINT;
        if (more) {
#pragma unroll
            for (int j = 0; j < 6; ++j) fn_[j] = feats[(tb + 6 + j) * L + n];
        }
        FWD_STEP(0, 1, 2, fc[0]);
        FWD_STEP(1, 2, 0, fc[1]);
        FWD_STEP(2, 0, 1, fc[2]);
        FWD_STEP(0, 1, 2, fc[3]);
        FWD_STEP(1, 2, 0, fc[4]);
        FWD_STEP(2, 0, 1, fc[5]);
        if (more) {
#pragma unroll
            for (int j = 0; j < 6; ++j) fc[j] = fn_[j];
        }
    }

    // tail: steps 199992..199999 (MAINT%3==0, so the rotation continues)
    float ft[8];
#pragma unroll
    for (int j = 0; j < 8; ++j) ft[j] = feats[(MAINT + j) * L + n];
    FWD_STEP(0, 1, 2, ft[0]);
    FWD_STEP(1, 2, 0, ft[1]);
    FWD_STEP(2, 0, 1, ft[2]);
    FWD_STEP(0, 1, 2, ft[3]);
    FWD_STEP(1, 2, 0, ft[4]);
    FWD_STEP(2, 0, 1, ft[5]);
    FWD_STEP(0, 1, 2, ft[6]);
    FWD_STEP(1, 2, 0, ft[7]);
    // v_{199999} lives in vbuf[200000 % 3] = vbuf[2]
    if (w == 0) ckpt[NCH * L + n] = vbuf[2][n];
#undef FWD_STEP
}

// ---------------------------------------------------------------------------
// helpers for the replay kernels (off the critical path, ~0.8 ms total)
// ---------------------------------------------------------------------------
__device__ __forceinline__ void load_trow(const float* __restrict__ trans, int n, float* trow) {
#pragma unroll
    for (int i = 0; i < 16; ++i) {
        const f32x4 q = reinterpret_cast<const f32x4*>(trans)[n * 16 + i];
        trow[4 * i + 0] = q.x;
        trow[4 * i + 1] = q.y;
        trow[4 * i + 2] = q.z;
        trow[4 * i + 3] = q.w;
    }
}

// Bit-exact chunk replay from checkpoint; records backpointers into LDS.
// Single wave per block; in-order DS pipe makes ds_write->ds_read safe with
// only a compiler barrier. Argmax is an in-order strictly-greater scan =>
// first-max, matching jnp.argmax; v matches k_forward bit-for-bit (max is
// order-invariant, +feat monotone-exact).
__device__ __forceinline__ void replay_chunk(const float* __restrict__ feats,
                                             const float* __restrict__ ckpt,
                                             const float* trow, float* vsh,
                                             unsigned char* bpl, int c, int len, int n) {
    float vreg = ckpt[c * L + n];
    vsh[n] = vreg;
    STEP_BARRIER();
    const int base = c * CH;

    float fc[8];
#pragma unroll
    for (int j = 0; j < 8; ++j) fc[j] = feats[(base + j) * L + n];

    for (int sb = 0; sb < len; sb += 8) {
        float fn_[8];
        const bool more = (sb + 8) < len;
        if (more) {
#pragma unroll
            for (int j = 0; j < 8; ++j) fn_[j] = feats[(base + sb + 8 + j) * L + n];
        }
#pragma unroll
        for (int j = 0; j < 8; ++j) {
            float mc[4];
            int ic[4];
#pragma unroll
            for (int g = 0; g < 4; ++g) {
                float m = -INFINITY;
                int idx = g * 16;
#pragma unroll
                for (int r = 0; r < 4; ++r) {
                    const int pb = g * 16 + r * 4;
                    const f32x4 vv = *reinterpret_cast<const f32x4*>(vsh + pb);
                    const float a = vv.x + trow[pb + 0];
                    const float b = vv.y + trow[pb + 1];
                    const float cc = vv.z + trow[pb + 2];
                    const float d = vv.w + trow[pb + 3];
                    if (a > m)  { m = a;  idx = pb + 0; }
                    if (b > m)  { m = b;  idx = pb + 1; }
                    if (cc > m) { m = cc; idx = pb + 2; }
                    if (d > m)  { m = d;  idx = pb + 3; }
                }
                mc[g] = m;
                ic[g] = idx;
            }
            float m = mc[0];
            int idx = ic[0];
            if (mc[1] > m) { m = mc[1]; idx = ic[1]; }
            if (mc[2] > m) { m = mc[2]; idx = ic[2]; }
            if (mc[3] > m) { m = mc[3]; idx = ic[3]; }

            vreg = m + fc[j];
            bpl[(sb + j) * L + n] = (unsigned char)idx;
            vsh[n] = vreg;
            STEP_BARRIER();
        }
        if (more) {
#pragma unroll
            for (int j = 0; j < 8; ++j) fc[j] = fn_[j];
        }
    }
}

// ---------------------------------------------------------------------------
// Pass 2: per-chunk bit-exact replay -> backpointers -> 64-entry chunk map.
// M[c*64+e] = tag at (c*CH - 1) given tag e at the last step of chunk c.
// ---------------------------------------------------------------------------
__global__ __launch_bounds__(64, 1) void k_maps(const float* __restrict__ feats,
                                                const float* __restrict__ trans,
                                                const float* __restrict__ ckpt,
                                                unsigned char* __restrict__ M) {
    const int c = blockIdx.x;
    const int n = threadIdx.x;
    const int len = (c == NCH - 1) ? LASTLEN : CH;

    __shared__ __align__(16) float vsh[L];
    __shared__ unsigned char bpl[CH * L];

    float trow[L];
    load_trow(trans, n, trow);
    replay_chunk(feats, ckpt, trow, vsh, bpl, c, len, n);
    __syncthreads();

    int tag = n;
    for (int s = len - 1; s >= 0; --s) tag = bpl[s * L + tag];
    M[c * L + n] = (unsigned char)tag;
}

// ---------------------------------------------------------------------------
// Pass 3: terminal argmax (bit-exact score) + back-to-front map composition.
// ---------------------------------------------------------------------------
__global__ __launch_bounds__(64, 1) void k_stitch(const float* __restrict__ trans,
                                                  const float* __restrict__ ckpt,
                                                  const unsigned char* __restrict__ M,
                                                  int* __restrict__ etag,
                                                  float* __restrict__ out) {
    const int n = threadIdx.x;
    __shared__ float tsh[L];
    __shared__ int bsh;
    __shared__ __align__(16) unsigned char msh[NCH * L];

    tsh[n] = ckpt[NCH * L + n] + trans[STOPT * L + n];  // terminal[n]
    __syncthreads();
    if (n == 0) {
        float m = tsh[0];
        int b = 0;
        for (int p = 1; p < L; ++p)
            if (tsh[p] > m) { m = tsh[p]; b = p; }  // first-max, like jnp.argmax
        out[0] = m;   // path_score, bit-exact
        bsh = b;
    }
    __syncthreads();

    for (int i = n; i < (NCH * L) / 4; i += L)
        reinterpret_cast<int*>(msh)[i] = reinterpret_cast<const int*>(M)[i];
    __syncthreads();

    if (n == 0) {
        int carry = bsh;  // tag at t = T-1 = end of chunk NCH-1
        for (int c = NCH - 1; c >= 1; --c) {
            etag[c] = carry;
            carry = msh[c * L + carry];
        }
        etag[0] = carry;
    }
}

// ---------------------------------------------------------------------------
// Pass 4: per-chunk replay again, walk backwards from etag[c], emit path.
// Path written as float32 (harness reads the concatenated output as float).
// ---------------------------------------------------------------------------
__global__ __launch_bounds__(64, 1) void k_emit(const float* __restrict__ feats,
                                                const float* __restrict__ trans,
                                                const float* __restrict__ ckpt,
                                                const int* __restrict__ etag,
                                                float* __restrict__ out) {
    const int c = blockIdx.x;
    const int n = threadIdx.x;
    const int len = (c == NCH - 1) ? LASTLEN : CH;

    __shared__ __align__(16) float vsh[L];
    __shared__ unsigned char bpl[CH * L];
    __shared__ unsigned char plc[CH];

    float trow[L];
    load_trow(trans, n, trow);
    replay_chunk(feats, ckpt, trow, vsh, bpl, c, len, n);
    __syncthreads();

    int tag = etag[c];  // uniform; bpl reads below broadcast (same address)
    for (int s = len - 1; s >= 0; --s) {
        if (n == 0) plc[s] = (unsigned char)tag;
        tag = bpl[s * L + tag];
    }
    __syncthreads();

    for (int i = n; i < len; i += L)
        out[1 + c * CH + i] = (float)plc[i];
}

// ---------------------------------------------------------------------------
extern "C" void kernel_launch(void* const* d_in, const int* in_sizes, int n_in,
                              void* d_out, int out_size, void* d_ws, size_t ws_size,
                              hipStream_t stream) {
    const float* feats = (const float*)d_in[0];   // (1, T, L) fp32
    const float* trans = (const float*)d_in[1];   // (L, L) fp32
    float* out = (float*)d_out;                   // [score, path(T) as float]
    char* ws = (char*)d_ws;
    float* ckpt = (float*)(ws + CKPT_OFF);
    unsigned char* M = (unsigned char*)(ws + M_OFF);
    int* etag = (int*)(ws + ETAG_OFF);

    hipLaunchKernelGGL(k_forward, dim3(1), dim3(512), 0, stream, feats, trans, ckpt);
    hipLaunchKernelGGL(k_maps, dim3(NCH), dim3(64), 0, stream, feats, trans, ckpt, M);
    hipLaunchKernelGGL(k_stitch, dim3(1), dim3(64), 0, stream, trans, ckpt, M, etag, out);
    hipLaunchKernelGGL(k_emit, dim3(NCH), dim3(64), 0, stream, feats, trans, ckpt, etag, out);
}